// Round 1
// baseline (1071.079 us; speedup 1.0000x reference)
//
#include <hip/hip_runtime.h>
#include <hip/hip_cooperative_groups.h>
#include <stdint.h>

namespace cg = cooperative_groups;

#define NROWS 1024
#define NCOLS 16384
#define NRB 64        // row tiles (16 rows each)
#define NCB 16        // col tiles (1024 cols each)
#define TROWS 16      // rows per tile
#define NROUNDS 3
#define NBLK (NRB * NCB)   // 1024 blocks = 4/CU (guaranteed by launch_bounds(256,4))

typedef unsigned long long u64;
typedef unsigned int u32;

// Persistent device state. Everything is written each call before being read:
// partials + col_used/cnt by scan phase; rowbest/assigned/rem by commit phase.
__device__ u64 g_rowpart[NCB * NROWS];         // per col-tile row maxima
__device__ u64 g_colpart[(size_t)NRB * NCOLS]; // per row-tile col maxima (8 MB)
__device__ u64 g_rowbest[NROWS];               // key: (sortable<<32)|(NCOLS-1-col)
__device__ int g_col_used[NCOLS];
__device__ int g_row_assigned[NROWS];
__device__ int g_rem[2][NROWS];                // double-buffered remaining lists
__device__ int g_cnt[NROUNDS + 1];             // list counts per round

// Monotone float32 -> uint32 mapping (preserves <):
__device__ __forceinline__ u32 fsort(float x) {
    u32 u = __float_as_uint(x);
    return u ^ ((u32)((int)u >> 31) | 0x80000000u);
}

__device__ __forceinline__ u64 wave_reduce_max(u64 v) {
    for (int off = 32; off; off >>= 1) {
        u64 o = __shfl_down(v, off);
        if (o > v) v = o;
    }
    return v;   // valid in lane 0
}

// blockDim == 256 (4 waves)
__device__ __forceinline__ u64 block_reduce_max(u64 v, u64* s_part) {
    v = wave_reduce_max(v);
    int wave = threadIdx.x >> 6;
    if ((threadIdx.x & 63) == 0) s_part[wave] = v;
    __syncthreads();
    u64 b = s_part[0];
    for (int w = 1; w < 4; w++) if (s_part[w] > b) b = s_part[w];
    __syncthreads();
    return b;
}

// ---------- Phase 1: tile scan. fb in [0, NBLK), 256 threads ----------
// Tile = 16 rows x 1024 cols. Col maxima in registers -> plain colpart stores;
// row maxima via per-row wave shuffle-reduce. Absorbs all state init.
__device__ __forceinline__ void phase_scan(const float* __restrict__ cost,
                                           int fb, int tid, u64 (*s_row)[4]) {
    const int cb = fb & (NCB - 1);
    const int rb = fb >> 4;
    const int cbase = cb * 1024;
    const int r0 = rb * TROWS;
    const int c0 = cbase + tid * 4;
    const int wv = tid >> 6, lane = tid & 63;

    if (rb == 0) {     // init: each cb-block zeroes its col_used slice
        int4 z; z.x = 0; z.y = 0; z.z = 0; z.w = 0;
        ((int4*)(g_col_used + cbase))[tid] = z;
        if (cb == 0 && tid <= NROUNDS) g_cnt[tid] = 0;
    }

    u64 b0 = 0, b1 = 0, b2 = 0, b3 = 0;
    for (int i = 0; i < TROWS; ++i) {
        int r = r0 + i;
        float4 v = *(const float4*)(cost + (size_t)r * NCOLS + c0);
        u32 rk = (u32)(NROWS - 1 - r);
        u64 k0 = ((u64)fsort(v.x) << 32) | rk;
        u64 k1 = ((u64)fsort(v.y) << 32) | rk;
        u64 k2 = ((u64)fsort(v.z) << 32) | rk;
        u64 k3 = ((u64)fsort(v.w) << 32) | rk;
        if (k0 > b0) b0 = k0;
        if (k1 > b1) b1 = k1;
        if (k2 > b2) b2 = k2;
        if (k3 > b3) b3 = k3;
        // row max for this row: re-key with column id (ties -> smaller col)
        u64 m0 = ((u64)fsort(v.x) << 32) | (u32)(NCOLS - 1 - (c0 + 0));
        u64 m1 = ((u64)fsort(v.y) << 32) | (u32)(NCOLS - 1 - (c0 + 1));
        u64 m2 = ((u64)fsort(v.z) << 32) | (u32)(NCOLS - 1 - (c0 + 2));
        u64 m3 = ((u64)fsort(v.w) << 32) | (u32)(NCOLS - 1 - (c0 + 3));
        u64 m = m0;
        if (m1 > m) m = m1;
        if (m2 > m) m = m2;
        if (m3 > m) m = m3;
        m = wave_reduce_max(m);
        if (lane == 0) s_row[i][wv] = m;
    }
    size_t cp = (size_t)rb * NCOLS + c0;
    g_colpart[cp + 0] = b0;
    g_colpart[cp + 1] = b1;
    g_colpart[cp + 2] = b2;
    g_colpart[cp + 3] = b3;
    __syncthreads();
    if (tid < TROWS) {
        u64 m = s_row[tid][0];
        if (s_row[tid][1] > m) m = s_row[tid][1];
        if (s_row[tid][2] > m) m = s_row[tid][2];
        if (s_row[tid][3] > m) m = s_row[tid][3];
        g_rowpart[cb * NROWS + (r0 + tid)] = m;
    }
}

// ---------- Phase 2: mutual-best commit. One wave per row r ----------
// Combine 16 rowparts (redundant 4x, wave-reduced), gather the candidate
// column's 64 colparts (1 per lane), round-0 mutual-best commit.
__device__ __forceinline__ void phase_commit(int* __restrict__ out, int r, int lane) {
    u64 v = g_rowpart[(lane & 15) * NROWS + r];
    u64 key = wave_reduce_max(v);
    key = __shfl(key, 0);                       // broadcast
    int c = NCOLS - 1 - (int)(key & 0xFFFFFFFFu);

    u64 cp = g_colpart[(size_t)lane * NCOLS + c];
    u64 colmax = wave_reduce_max(cp);           // lane 0

    if (lane == 0) {
        g_rowbest[r] = key;
        out[r] = r;                             // identity row indices
        u64 mk = (key & 0xFFFFFFFF00000000ULL) | (u32)(NROWS - 1 - r);
        if (colmax == mk) {                     // mutual best -> commit
            g_col_used[c] = 1;
            g_row_assigned[r] = 1;
            out[NROWS + r] = c;
        } else {
            g_row_assigned[r] = 0;
            int p = atomicAdd(&g_cnt[0], 1);
            g_rem[0][p] = r;
        }
    }
}

// ---------- Per-round phase (256 threads, block = row r) ----------
// Assigned rows exit instantly. (a) rescan own row if cached best col was
// taken; (b) winner check against raw cost values of rows remaining at round
// start. Within-round col_used races are benign (losers retry next round).
__device__ __forceinline__ void phase_round(const float* __restrict__ cost,
                                            int* __restrict__ out, int t, int r,
                                            int tid, u64* s_part) {
    if (g_row_assigned[r]) return;      // block-uniform

    u64 key = g_rowbest[r];
    int c = NCOLS - 1 - (int)(key & 0xFFFFFFFFu);
    if (g_col_used[c]) {              // stale -> rescan excluding used cols
        u64 best = 0ULL;
        const float4* row = (const float4*)(cost + (size_t)r * NCOLS);
        const int4* used = (const int4*)g_col_used;
        for (int k = tid; k < NCOLS / 4; k += 256) {
            float4 v = row[k];
            int4 u = used[k];
            int c0 = k * 4;
            if (!u.x) { u64 kk = ((u64)fsort(v.x) << 32) | (u32)(NCOLS - 1 - (c0 + 0)); if (kk > best) best = kk; }
            if (!u.y) { u64 kk = ((u64)fsort(v.y) << 32) | (u32)(NCOLS - 1 - (c0 + 1)); if (kk > best) best = kk; }
            if (!u.z) { u64 kk = ((u64)fsort(v.z) << 32) | (u32)(NCOLS - 1 - (c0 + 2)); if (kk > best) best = kk; }
            if (!u.w) { u64 kk = ((u64)fsort(v.w) << 32) | (u32)(NCOLS - 1 - (c0 + 3)); if (kk > best) best = kk; }
        }
        key = block_reduce_max(best, s_part);
        if (tid == 0) g_rowbest[r] = key;
        c = NCOLS - 1 - (int)(key & 0xFFFFFFFFu);
    }

    int n = g_cnt[t];
    const int* list = g_rem[t & 1];
    u64 mine = (key & 0xFFFFFFFF00000000ULL) | (u32)(NROWS - 1 - r);
    u64 mx = 0ULL;
    for (int j = tid; j < n; j += 256) {
        int rj = list[j];
        if (rj != r) {
            float x = cost[(size_t)rj * NCOLS + c];
            u64 kj = ((u64)fsort(x) << 32) | (u32)(NROWS - 1 - rj);
            if (kj > mx) mx = kj;
        }
    }
    mx = block_reduce_max(mx, s_part);
    if (tid == 0) {
        if (mine > mx) {              // unique max at col c among survivors
            g_col_used[c] = 1;
            g_row_assigned[r] = 1;
            out[NROWS + r] = c;
        } else {
            int p = atomicAdd(&g_cnt[t + 1], 1);
            g_rem[(t + 1) & 1][p] = r;
        }
    }
}

// ---------- Final serial cleanup, single block of 256 ----------
// Normally sees n==0 or tiny n. Win checks are independent of commits, so
// chunking by 256 (for robustness vs n>256) preserves semantics.
__device__ __forceinline__ void phase_finish(const float* __restrict__ cost,
                                             int* __restrict__ out, int tid,
                                             int (*s_rem)[NROWS], u64* s_part,
                                             int* s_nn) {
    if (tid == 0) s_nn[0] = g_cnt[NROUNDS];
    __syncthreads();
    int n = s_nn[0];
    if (n == 0) return;
    for (int i = tid; i < n; i += 256) s_rem[0][i] = g_rem[NROUNDS & 1][i];
    __syncthreads();
    int cur = 0;
    while (n > 0) {
        // rescan rows whose cached best col was taken
        for (int i = 0; i < n; i++) {
            int r = s_rem[cur][i];
            u64 key = g_rowbest[r];
            int c = NCOLS - 1 - (int)(key & 0xFFFFFFFFu);
            if (g_col_used[c]) {
                u64 best = 0ULL;
                const float4* row = (const float4*)(cost + (size_t)r * NCOLS);
                const int4* used4 = (const int4*)g_col_used;
                for (int k = tid; k < NCOLS / 4; k += 256) {
                    float4 v = row[k];
                    int4 u = used4[k];
                    int c0 = k * 4;
                    if (!u.x) { u64 kk = ((u64)fsort(v.x) << 32) | (u32)(NCOLS - 1 - (c0 + 0)); if (kk > best) best = kk; }
                    if (!u.y) { u64 kk = ((u64)fsort(v.y) << 32) | (u32)(NCOLS - 1 - (c0 + 1)); if (kk > best) best = kk; }
                    if (!u.z) { u64 kk = ((u64)fsort(v.z) << 32) | (u32)(NCOLS - 1 - (c0 + 2)); if (kk > best) best = kk; }
                    if (!u.w) { u64 kk = ((u64)fsort(v.w) << 32) | (u32)(NCOLS - 1 - (c0 + 3)); if (kk > best) best = kk; }
                }
                u64 m = block_reduce_max(best, s_part);
                if (tid == 0) g_rowbest[r] = m;
            }
        }
        __syncthreads();
        if (tid == 0) s_nn[1] = 0;
        __syncthreads();
        for (int base = 0; base < n; base += 256) {
            bool win = false; int myr = -1, myc = -1;
            if (base + tid < n) {
                int r = s_rem[cur][base + tid];
                u64 key = g_rowbest[r];
                int c = NCOLS - 1 - (int)(key & 0xFFFFFFFFu);
                u64 mine = (key & 0xFFFFFFFF00000000ULL) | (u32)(NROWS - 1 - r);
                win = true;
                for (int j = 0; j < n; j++) {
                    int rj = s_rem[cur][j];
                    if (rj == r) continue;
                    float x = cost[(size_t)rj * NCOLS + c];
                    u64 kj = ((u64)fsort(x) << 32) | (u32)(NROWS - 1 - rj);
                    if (kj > mine) { win = false; break; }
                }
                myr = r; myc = c;
            }
            if (win) {
                g_col_used[myc] = 1; g_row_assigned[myr] = 1; out[NROWS + myr] = myc;
            }
            if (base + tid < n && !win) {
                int p = atomicAdd(&s_nn[1], 1);
                s_rem[cur ^ 1][p] = myr;
            }
        }
        __syncthreads();
        n = s_nn[1];
        cur ^= 1;
        __syncthreads();
    }
}

// ---------- Fused cooperative kernel: all phases, one dispatch ----------
// 1024 blocks x 256; launch_bounds(256,4) caps VGPR at 128 -> 4 blocks/CU
// guaranteed -> exactly co-resident for cooperative launch. grid.sync() +
// __threadfence() replaces kernel boundaries (device-scope visibility).
__global__ void __launch_bounds__(256, 4)
k_fused(const float* __restrict__ cost, int* __restrict__ out) {
    __shared__ u64 s_row[TROWS][4];
    __shared__ u64 s_part[4];
    __shared__ int s_rem[2][NROWS];
    __shared__ int s_nn[2];
    const int bid = blockIdx.x;
    const int tid = threadIdx.x;
    cg::grid_group grid = cg::this_grid();

    phase_scan(cost, bid, tid, s_row);
    __threadfence();
    grid.sync();

    if (tid < 64) phase_commit(out, bid, tid);
    __threadfence();
    grid.sync();

    for (int t = 0; t < NROUNDS; ++t) {
        phase_round(cost, out, t, bid, tid, s_part);
        __threadfence();
        grid.sync();
    }

    if (bid == 0) phase_finish(cost, out, tid, s_rem, s_part, s_nn);
}

// ---------- Fallback path (plain launches), used only if coop launch fails ----------
__global__ void __launch_bounds__(256) k_scan2(const float* __restrict__ cost) {
    __shared__ u64 s_row[TROWS][4];
    phase_scan(cost, blockIdx.x, threadIdx.x, s_row);
}
__global__ void __launch_bounds__(64) k_commit2(int* __restrict__ out) {
    phase_commit(out, blockIdx.x, threadIdx.x);
}
__global__ void __launch_bounds__(256) k_round2(const float* __restrict__ cost,
                                                int* __restrict__ out, int t) {
    __shared__ u64 s_part[4];
    phase_round(cost, out, t, blockIdx.x, threadIdx.x, s_part);
}
__global__ void __launch_bounds__(256) k_finish2(const float* __restrict__ cost,
                                                 int* __restrict__ out) {
    __shared__ int s_rem[2][NROWS];
    __shared__ u64 s_part[4];
    __shared__ int s_nn[2];
    phase_finish(cost, out, threadIdx.x, s_rem, s_part, s_nn);
}

extern "C" void kernel_launch(void* const* d_in, const int* in_sizes, int n_in,
                              void* d_out, int out_size, void* d_ws, size_t ws_size,
                              hipStream_t stream) {
    const float* cost = (const float*)d_in[0];
    int* out = (int*)d_out;

    void* args[] = {(void*)&cost, (void*)&out};
    hipError_t e = hipLaunchCooperativeKernel(k_fused, dim3(NBLK), dim3(256),
                                              args, 0u, stream);
    if (e != hipSuccess) {
        // cooperative launch refused -> proven multi-dispatch path
        k_scan2<<<NBLK, 256, 0, stream>>>(cost);
        k_commit2<<<NROWS, 64, 0, stream>>>(out);
        for (int t = 0; t < NROUNDS; ++t)
            k_round2<<<NROWS, 256, 0, stream>>>(cost, out, t);
        k_finish2<<<1, 256, 0, stream>>>(cost, out);
    }
}

// Round 2
// 970.054 us; speedup vs baseline: 1.1041x; 1.1041x over previous
//
#include <hip/hip_runtime.h>
#include <stdint.h>

#define NROWS 1024
#define NCOLS 16384
#define NRB 64        // row tiles (16 rows each)
#define NCB 16        // col tiles (1024 cols each)
#define TROWS 16      // rows per tile
#define NROUNDS 2
#define NBLK (NRB * NCB)   // 1024 blocks = 4/CU (guaranteed by launch_bounds(256,4))

#define NLEAF 64
#define LEAFSZ (NBLK / NLEAF)   // 16 arrivals per leaf

typedef unsigned long long u64;
typedef unsigned int u32;

// Persistent device state. Everything is written each call before being read:
// partials + col_used/cnt by scan phase; rowbest/assigned/rem by commit phase.
__device__ u64 g_rowpart[NCB * NROWS];         // per col-tile row maxima
__device__ u64 g_colpart[(size_t)NRB * NCOLS]; // per row-tile col maxima (8 MB)
__device__ u64 g_rowbest[NROWS];               // key: (sortable<<32)|(NCOLS-1-col)
__device__ int g_col_used[NCOLS];
__device__ int g_row_assigned[NROWS];
__device__ int g_rem[2][NROWS];                // double-buffered remaining lists
__device__ int g_cnt[NROUNDS + 1];             // list counts per round

// Custom tree barrier state. Leaf/root self-reset each use; gen is monotone
// (persists across launches; each barrier call snapshots it before arriving).
__device__ int g_bar_leaf[NLEAF * 16];         // one 64B line per leaf
__device__ int g_bar_root;
__device__ int g_bar_gen;

// Two-level combining-tree grid barrier. Replaces cg::grid.sync(), whose
// escalating s_sleep backoff cost ~190us/sync at 1024 blocks (round-1 data:
// VALUBusy 0.8%, 53 GB/s over 1015us = sleeping waves). tid0-only spin with
// fixed tiny sleep; acq-rel chain makes the leaf self-reset race-free:
// leaf reset -> ACQ_REL root add -> RELEASE gen bump -> ACQUIRE spin load.
// __threadfence (agent fence: buffer_wbl2/buffer_inv) before arrival / after
// release gives cross-XCD data visibility, same contract as a kernel boundary.
__device__ __forceinline__ void grid_barrier(int bid, int tid) {
    __syncthreads();
    if (tid == 0) {
        __threadfence();   // release our block's data writes (L2 writeback)
        int gen = __hip_atomic_load(&g_bar_gen, __ATOMIC_RELAXED,
                                    __HIP_MEMORY_SCOPE_AGENT);
        int leaf = (bid & (NLEAF - 1)) * 16;
        if (__hip_atomic_fetch_add(&g_bar_leaf[leaf], 1, __ATOMIC_ACQ_REL,
                                   __HIP_MEMORY_SCOPE_AGENT) == LEAFSZ - 1) {
            __hip_atomic_store(&g_bar_leaf[leaf], 0, __ATOMIC_RELAXED,
                               __HIP_MEMORY_SCOPE_AGENT);
            if (__hip_atomic_fetch_add(&g_bar_root, 1, __ATOMIC_ACQ_REL,
                                       __HIP_MEMORY_SCOPE_AGENT) == NLEAF - 1) {
                __hip_atomic_store(&g_bar_root, 0, __ATOMIC_RELAXED,
                                   __HIP_MEMORY_SCOPE_AGENT);
                __hip_atomic_fetch_add(&g_bar_gen, 1, __ATOMIC_RELEASE,
                                       __HIP_MEMORY_SCOPE_AGENT);
            }
        }
        while (__hip_atomic_load(&g_bar_gen, __ATOMIC_ACQUIRE,
                                 __HIP_MEMORY_SCOPE_AGENT) == gen) {
            __builtin_amdgcn_s_sleep(1);   // fixed ~64cy nap, no escalation
        }
        __threadfence();   // acquire: invalidate stale L1/L2 lines
    }
    __syncthreads();
}

// Monotone float32 -> uint32 mapping (preserves <):
__device__ __forceinline__ u32 fsort(float x) {
    u32 u = __float_as_uint(x);
    return u ^ ((u32)((int)u >> 31) | 0x80000000u);
}

__device__ __forceinline__ u64 wave_reduce_max(u64 v) {
    for (int off = 32; off; off >>= 1) {
        u64 o = __shfl_down(v, off);
        if (o > v) v = o;
    }
    return v;   // valid in lane 0
}

// blockDim == 256 (4 waves)
__device__ __forceinline__ u64 block_reduce_max(u64 v, u64* s_part) {
    v = wave_reduce_max(v);
    int wave = threadIdx.x >> 6;
    if ((threadIdx.x & 63) == 0) s_part[wave] = v;
    __syncthreads();
    u64 b = s_part[0];
    for (int w = 1; w < 4; w++) if (s_part[w] > b) b = s_part[w];
    __syncthreads();
    return b;
}

// ---------- Phase 1: tile scan. fb in [0, NBLK), 256 threads ----------
// Tile = 16 rows x 1024 cols. Col maxima in registers -> plain colpart stores;
// row maxima via per-row wave shuffle-reduce. Absorbs all state init.
__device__ __forceinline__ void phase_scan(const float* __restrict__ cost,
                                           int fb, int tid, u64 (*s_row)[4]) {
    const int cb = fb & (NCB - 1);
    const int rb = fb >> 4;
    const int cbase = cb * 1024;
    const int r0 = rb * TROWS;
    const int c0 = cbase + tid * 4;
    const int wv = tid >> 6, lane = tid & 63;

    if (rb == 0) {     // init: each cb-block zeroes its col_used slice
        int4 z; z.x = 0; z.y = 0; z.z = 0; z.w = 0;
        ((int4*)(g_col_used + cbase))[tid] = z;
        if (cb == 0 && tid <= NROUNDS) g_cnt[tid] = 0;
    }

    u64 b0 = 0, b1 = 0, b2 = 0, b3 = 0;
    for (int i = 0; i < TROWS; ++i) {
        int r = r0 + i;
        float4 v = *(const float4*)(cost + (size_t)r * NCOLS + c0);
        u32 rk = (u32)(NROWS - 1 - r);
        u64 k0 = ((u64)fsort(v.x) << 32) | rk;
        u64 k1 = ((u64)fsort(v.y) << 32) | rk;
        u64 k2 = ((u64)fsort(v.z) << 32) | rk;
        u64 k3 = ((u64)fsort(v.w) << 32) | rk;
        if (k0 > b0) b0 = k0;
        if (k1 > b1) b1 = k1;
        if (k2 > b2) b2 = k2;
        if (k3 > b3) b3 = k3;
        // row max for this row: re-key with column id (ties -> smaller col)
        u64 m0 = ((u64)fsort(v.x) << 32) | (u32)(NCOLS - 1 - (c0 + 0));
        u64 m1 = ((u64)fsort(v.y) << 32) | (u32)(NCOLS - 1 - (c0 + 1));
        u64 m2 = ((u64)fsort(v.z) << 32) | (u32)(NCOLS - 1 - (c0 + 2));
        u64 m3 = ((u64)fsort(v.w) << 32) | (u32)(NCOLS - 1 - (c0 + 3));
        u64 m = m0;
        if (m1 > m) m = m1;
        if (m2 > m) m = m2;
        if (m3 > m) m = m3;
        m = wave_reduce_max(m);
        if (lane == 0) s_row[i][wv] = m;
    }
    size_t cp = (size_t)rb * NCOLS + c0;
    g_colpart[cp + 0] = b0;
    g_colpart[cp + 1] = b1;
    g_colpart[cp + 2] = b2;
    g_colpart[cp + 3] = b3;
    __syncthreads();
    if (tid < TROWS) {
        u64 m = s_row[tid][0];
        if (s_row[tid][1] > m) m = s_row[tid][1];
        if (s_row[tid][2] > m) m = s_row[tid][2];
        if (s_row[tid][3] > m) m = s_row[tid][3];
        g_rowpart[cb * NROWS + (r0 + tid)] = m;
    }
}

// ---------- Phase 2: mutual-best commit. One wave per row r ----------
// Combine 16 rowparts (redundant 4x, wave-reduced), gather the candidate
// column's 64 colparts (1 per lane), round-0 mutual-best commit.
__device__ __forceinline__ void phase_commit(int* __restrict__ out, int r, int lane) {
    u64 v = g_rowpart[(lane & 15) * NROWS + r];
    u64 key = wave_reduce_max(v);
    key = __shfl(key, 0);                       // broadcast
    int c = NCOLS - 1 - (int)(key & 0xFFFFFFFFu);

    u64 cp = g_colpart[(size_t)lane * NCOLS + c];
    u64 colmax = wave_reduce_max(cp);           // lane 0

    if (lane == 0) {
        g_rowbest[r] = key;
        out[r] = r;                             // identity row indices
        u64 mk = (key & 0xFFFFFFFF00000000ULL) | (u32)(NROWS - 1 - r);
        if (colmax == mk) {                     // mutual best -> commit
            g_col_used[c] = 1;
            g_row_assigned[r] = 1;
            out[NROWS + r] = c;
        } else {
            g_row_assigned[r] = 0;
            int p = atomicAdd(&g_cnt[0], 1);
            g_rem[0][p] = r;
        }
    }
}

// ---------- Per-round phase (256 threads, block = row r) ----------
// Assigned rows exit instantly. (a) rescan own row if cached best col was
// taken; (b) winner check against raw cost values of rows remaining at round
// start. Within-round col_used races are benign (losers retry next round).
__device__ __forceinline__ void phase_round(const float* __restrict__ cost,
                                            int* __restrict__ out, int t, int r,
                                            int tid, u64* s_part) {
    if (g_row_assigned[r]) return;      // block-uniform

    u64 key = g_rowbest[r];
    int c = NCOLS - 1 - (int)(key & 0xFFFFFFFFu);
    if (g_col_used[c]) {              // stale -> rescan excluding used cols
        u64 best = 0ULL;
        const float4* row = (const float4*)(cost + (size_t)r * NCOLS);
        const int4* used = (const int4*)g_col_used;
        for (int k = tid; k < NCOLS / 4; k += 256) {
            float4 v = row[k];
            int4 u = used[k];
            int c0 = k * 4;
            if (!u.x) { u64 kk = ((u64)fsort(v.x) << 32) | (u32)(NCOLS - 1 - (c0 + 0)); if (kk > best) best = kk; }
            if (!u.y) { u64 kk = ((u64)fsort(v.y) << 32) | (u32)(NCOLS - 1 - (c0 + 1)); if (kk > best) best = kk; }
            if (!u.z) { u64 kk = ((u64)fsort(v.z) << 32) | (u32)(NCOLS - 1 - (c0 + 2)); if (kk > best) best = kk; }
            if (!u.w) { u64 kk = ((u64)fsort(v.w) << 32) | (u32)(NCOLS - 1 - (c0 + 3)); if (kk > best) best = kk; }
        }
        key = block_reduce_max(best, s_part);
        if (tid == 0) g_rowbest[r] = key;
        c = NCOLS - 1 - (int)(key & 0xFFFFFFFFu);
    }

    int n = g_cnt[t];
    const int* list = g_rem[t & 1];
    u64 mine = (key & 0xFFFFFFFF00000000ULL) | (u32)(NROWS - 1 - r);
    u64 mx = 0ULL;
    for (int j = tid; j < n; j += 256) {
        int rj = list[j];
        if (rj != r) {
            float x = cost[(size_t)rj * NCOLS + c];
            u64 kj = ((u64)fsort(x) << 32) | (u32)(NROWS - 1 - rj);
            if (kj > mx) mx = kj;
        }
    }
    mx = block_reduce_max(mx, s_part);
    if (tid == 0) {
        if (mine > mx) {              // unique max at col c among survivors
            g_col_used[c] = 1;
            g_row_assigned[r] = 1;
            out[NROWS + r] = c;
        } else {
            int p = atomicAdd(&g_cnt[t + 1], 1);
            g_rem[(t + 1) & 1][p] = r;
        }
    }
}

// ---------- Final serial cleanup, single block of 256 ----------
// Normally sees n==0 or tiny n. Win checks are independent of commits, so
// chunking by 256 (for robustness vs n>256) preserves semantics.
__device__ __forceinline__ void phase_finish(const float* __restrict__ cost,
                                             int* __restrict__ out, int tid,
                                             int (*s_rem)[NROWS], u64* s_part,
                                             int* s_nn) {
    if (tid == 0) s_nn[0] = g_cnt[NROUNDS];
    __syncthreads();
    int n = s_nn[0];
    if (n == 0) return;
    for (int i = tid; i < n; i += 256) s_rem[0][i] = g_rem[NROUNDS & 1][i];
    __syncthreads();
    int cur = 0;
    while (n > 0) {
        // rescan rows whose cached best col was taken
        for (int i = 0; i < n; i++) {
            int r = s_rem[cur][i];
            u64 key = g_rowbest[r];
            int c = NCOLS - 1 - (int)(key & 0xFFFFFFFFu);
            if (g_col_used[c]) {
                u64 best = 0ULL;
                const float4* row = (const float4*)(cost + (size_t)r * NCOLS);
                const int4* used4 = (const int4*)g_col_used;
                for (int k = tid; k < NCOLS / 4; k += 256) {
                    float4 v = row[k];
                    int4 u = used4[k];
                    int c0 = k * 4;
                    if (!u.x) { u64 kk = ((u64)fsort(v.x) << 32) | (u32)(NCOLS - 1 - (c0 + 0)); if (kk > best) best = kk; }
                    if (!u.y) { u64 kk = ((u64)fsort(v.y) << 32) | (u32)(NCOLS - 1 - (c0 + 1)); if (kk > best) best = kk; }
                    if (!u.z) { u64 kk = ((u64)fsort(v.z) << 32) | (u32)(NCOLS - 1 - (c0 + 2)); if (kk > best) best = kk; }
                    if (!u.w) { u64 kk = ((u64)fsort(v.w) << 32) | (u32)(NCOLS - 1 - (c0 + 3)); if (kk > best) best = kk; }
                }
                u64 m = block_reduce_max(best, s_part);
                if (tid == 0) g_rowbest[r] = m;
            }
        }
        __syncthreads();
        if (tid == 0) s_nn[1] = 0;
        __syncthreads();
        for (int base = 0; base < n; base += 256) {
            bool win = false; int myr = -1, myc = -1;
            if (base + tid < n) {
                int r = s_rem[cur][base + tid];
                u64 key = g_rowbest[r];
                int c = NCOLS - 1 - (int)(key & 0xFFFFFFFFu);
                u64 mine = (key & 0xFFFFFFFF00000000ULL) | (u32)(NROWS - 1 - r);
                win = true;
                for (int j = 0; j < n; j++) {
                    int rj = s_rem[cur][j];
                    if (rj == r) continue;
                    float x = cost[(size_t)rj * NCOLS + c];
                    u64 kj = ((u64)fsort(x) << 32) | (u32)(NROWS - 1 - rj);
                    if (kj > mine) { win = false; break; }
                }
                myr = r; myc = c;
            }
            if (win) {
                g_col_used[myc] = 1; g_row_assigned[myr] = 1; out[NROWS + myr] = myc;
            }
            if (base + tid < n && !win) {
                int p = atomicAdd(&s_nn[1], 1);
                s_rem[cur ^ 1][p] = myr;
            }
        }
        __syncthreads();
        n = s_nn[1];
        cur ^= 1;
        __syncthreads();
    }
}

// ---------- Fused kernel: all phases, one dispatch, custom barriers ----------
// 1024 blocks x 256; launch_bounds(256,4) caps VGPR at 128 -> 4 blocks/CU ->
// exactly co-resident (cooperative launch guarantees or errors out).
__global__ void __launch_bounds__(256, 4)
k_fused(const float* __restrict__ cost, int* __restrict__ out) {
    __shared__ u64 s_row[TROWS][4];
    __shared__ u64 s_part[4];
    __shared__ int s_rem[2][NROWS];
    __shared__ int s_nn[2];
    const int bid = blockIdx.x;
    const int tid = threadIdx.x;

    phase_scan(cost, bid, tid, s_row);
    grid_barrier(bid, tid);

    if (tid < 64) phase_commit(out, bid, tid);
    grid_barrier(bid, tid);

    phase_round(cost, out, 0, bid, tid, s_part);
    grid_barrier(bid, tid);

    phase_round(cost, out, 1, bid, tid, s_part);
    grid_barrier(bid, tid);

    if (bid == 0) phase_finish(cost, out, tid, s_rem, s_part, s_nn);
}

// ---------- Fallback path (plain launches), used only if coop launch fails ----------
__global__ void __launch_bounds__(256) k_scan2(const float* __restrict__ cost) {
    __shared__ u64 s_row[TROWS][4];
    phase_scan(cost, blockIdx.x, threadIdx.x, s_row);
}
__global__ void __launch_bounds__(64) k_commit2(int* __restrict__ out) {
    phase_commit(out, blockIdx.x, threadIdx.x);
}
__global__ void __launch_bounds__(256) k_round2(const float* __restrict__ cost,
                                                int* __restrict__ out, int t) {
    __shared__ u64 s_part[4];
    phase_round(cost, out, t, blockIdx.x, threadIdx.x, s_part);
}
__global__ void __launch_bounds__(256) k_finish2(const float* __restrict__ cost,
                                                 int* __restrict__ out) {
    __shared__ int s_rem[2][NROWS];
    __shared__ u64 s_part[4];
    __shared__ int s_nn[2];
    phase_finish(cost, out, threadIdx.x, s_rem, s_part, s_nn);
}

extern "C" void kernel_launch(void* const* d_in, const int* in_sizes, int n_in,
                              void* d_out, int out_size, void* d_ws, size_t ws_size,
                              hipStream_t stream) {
    const float* cost = (const float*)d_in[0];
    int* out = (int*)d_out;

    void* args[] = {(void*)&cost, (void*)&out};
    hipError_t e = hipLaunchCooperativeKernel(k_fused, dim3(NBLK), dim3(256),
                                              args, 0u, stream);
    if (e != hipSuccess) {
        // cooperative launch refused -> proven multi-dispatch path
        k_scan2<<<NBLK, 256, 0, stream>>>(cost);
        k_commit2<<<NROWS, 64, 0, stream>>>(out);
        for (int t = 0; t < NROUNDS; ++t)
            k_round2<<<NROWS, 256, 0, stream>>>(cost, out, t);
        k_finish2<<<1, 256, 0, stream>>>(cost, out);
    }
}

// Round 3
// 169.919 us; speedup vs baseline: 6.3035x; 5.7089x over previous
//
#include <hip/hip_runtime.h>
#include <stdint.h>

#define NROWS 1024
#define NCOLS 16384
#define NRB 64        // row tiles (16 rows each)
#define NCB 16        // col tiles (1024 cols each)
#define TROWS 16      // rows per tile
#define NROUNDS 2
#define NBLK (NRB * NCB)   // 1024 blocks = 4/CU (guaranteed by launch_bounds(256,4))

#define NLEAF 64
#define LEAFSZ (NBLK / NLEAF)   // 16 arrivals per leaf

typedef unsigned long long u64;
typedef unsigned int u32;

// Persistent device state. Everything is written each call before being read:
// partials + col_used/cnt by scan phase; rowbest/assigned/rem by commit phase.
__device__ u64 g_rowpart[NCB * NROWS];         // per col-tile row maxima
__device__ u64 g_colpart[(size_t)NRB * NCOLS]; // per row-tile col maxima (8 MB)
__device__ u64 g_rowbest[NROWS];               // key: (sortable<<32)|(NCOLS-1-col)
__device__ int g_col_used[NCOLS];
__device__ int g_row_assigned[NROWS];
__device__ int g_rem[2][NROWS];                // double-buffered remaining lists
__device__ int g_cnt[NROUNDS + 1];             // list counts per round

// Monotone (never-reset) tree-barrier counters. Zero-init at module load;
// all values advance in lockstep (1024 leaf arrivals = 64 root adds = 1 gen
// bump per barrier), so state is valid across launches and rocprof replays.
__device__ int g_bar_leaf[NLEAF * 32];         // one 128B line per leaf
__device__ int g_bar_root;
__device__ int g_bar_gen;

// ---- RELAXED agent-scope accessors: device-coherent via MALL, NO cache
// maintenance ops attached (the round-1/2 barrier cost was 2048 per-barrier
// buffer_wbl2/buffer_inv L2 tag-walks from __threadfence + ACQUIRE spins;
// ~200us/barrier at 1024 blocks, identical for cg::sync and custom tree).
__device__ __forceinline__ u64 ald64(const u64* p) {
    return __hip_atomic_load((u64*)p, __ATOMIC_RELAXED, __HIP_MEMORY_SCOPE_AGENT);
}
__device__ __forceinline__ void ast64(u64* p, u64 v) {
    __hip_atomic_store(p, v, __ATOMIC_RELAXED, __HIP_MEMORY_SCOPE_AGENT);
}
__device__ __forceinline__ int ald32(const int* p) {
    return __hip_atomic_load((int*)p, __ATOMIC_RELAXED, __HIP_MEMORY_SCOPE_AGENT);
}
__device__ __forceinline__ void ast32(int* p, int v) {
    __hip_atomic_store(p, v, __ATOMIC_RELAXED, __HIP_MEMORY_SCOPE_AGENT);
}
__device__ __forceinline__ int aadd32(int* p, int v) {
    return __hip_atomic_fetch_add(p, v, __ATOMIC_RELAXED, __HIP_MEMORY_SCOPE_AGENT);
}

// Fence-free grid barrier. Correctness chain: every thread drains its own
// vmem (stores acked at MALL) -> __syncthreads -> tid0 arrives. fetch_add
// return values give causal order leaf->root->gen at the MALL; a waiter that
// observes the gen bump therefore observes all pre-barrier MALL stores.
// gen snapshot must COMPLETE before our arrival can trigger the bump, hence
// the waitcnt between snapshot and arrive.
__device__ __forceinline__ void grid_barrier(int bid, int tid) {
    asm volatile("s_waitcnt vmcnt(0)" ::: "memory");   // all threads drain
    __syncthreads();
    if (tid == 0) {
        int gen = ald32(&g_bar_gen);
        asm volatile("s_waitcnt vmcnt(0)" ::: "memory");  // snapshot bound
        int leaf = (bid & (NLEAF - 1)) * 32;
        int v = aadd32(&g_bar_leaf[leaf], 1);
        if ((v & (LEAFSZ - 1)) == LEAFSZ - 1) {           // leaf complete
            int u = aadd32(&g_bar_root, 1);
            if ((u & (NLEAF - 1)) == NLEAF - 1) {         // grid complete
                aadd32(&g_bar_gen, 1);
            }
        }
        while (ald32(&g_bar_gen) == gen) {
            __builtin_amdgcn_s_sleep(8);   // ~512cy nap, no cache ops
        }
    }
    __syncthreads();
    asm volatile("" ::: "memory");
}

// Monotone float32 -> uint32 mapping (preserves <):
__device__ __forceinline__ u32 fsort(float x) {
    u32 u = __float_as_uint(x);
    return u ^ ((u32)((int)u >> 31) | 0x80000000u);
}

__device__ __forceinline__ u64 wave_reduce_max(u64 v) {
    for (int off = 32; off; off >>= 1) {
        u64 o = __shfl_down(v, off);
        if (o > v) v = o;
    }
    return v;   // valid in lane 0
}

// blockDim == 256 (4 waves)
__device__ __forceinline__ u64 block_reduce_max(u64 v, u64* s_part) {
    v = wave_reduce_max(v);
    int wave = threadIdx.x >> 6;
    if ((threadIdx.x & 63) == 0) s_part[wave] = v;
    __syncthreads();
    u64 b = s_part[0];
    for (int w = 1; w < 4; w++) if (s_part[w] > b) b = s_part[w];
    __syncthreads();
    return b;
}

// ---------- Phase 1: tile scan. fb in [0, NBLK), 256 threads ----------
// Tile = 16 rows x 1024 cols. Col maxima in registers -> agent colpart
// stores; row maxima via per-row wave shuffle-reduce. Absorbs state init.
__device__ __forceinline__ void phase_scan(const float* __restrict__ cost,
                                           int fb, int tid, u64 (*s_row)[4]) {
    const int cb = fb & (NCB - 1);
    const int rb = fb >> 4;
    const int cbase = cb * 1024;
    const int r0 = rb * TROWS;
    const int c0 = cbase + tid * 4;
    const int wv = tid >> 6, lane = tid & 63;

    if (rb == 0) {     // init: each cb-block zeroes its col_used slice (MALL)
        ast64((u64*)(g_col_used + cbase) + tid * 2 + 0, 0ULL);
        ast64((u64*)(g_col_used + cbase) + tid * 2 + 1, 0ULL);
        if (cb == 0 && tid <= NROUNDS) ast32(&g_cnt[tid], 0);
    }

    u64 b0 = 0, b1 = 0, b2 = 0, b3 = 0;
    for (int i = 0; i < TROWS; ++i) {
        int r = r0 + i;
        float4 v = *(const float4*)(cost + (size_t)r * NCOLS + c0);
        u32 rk = (u32)(NROWS - 1 - r);
        u64 k0 = ((u64)fsort(v.x) << 32) | rk;
        u64 k1 = ((u64)fsort(v.y) << 32) | rk;
        u64 k2 = ((u64)fsort(v.z) << 32) | rk;
        u64 k3 = ((u64)fsort(v.w) << 32) | rk;
        if (k0 > b0) b0 = k0;
        if (k1 > b1) b1 = k1;
        if (k2 > b2) b2 = k2;
        if (k3 > b3) b3 = k3;
        // row max for this row: re-key with column id (ties -> smaller col)
        u64 m0 = ((u64)fsort(v.x) << 32) | (u32)(NCOLS - 1 - (c0 + 0));
        u64 m1 = ((u64)fsort(v.y) << 32) | (u32)(NCOLS - 1 - (c0 + 1));
        u64 m2 = ((u64)fsort(v.z) << 32) | (u32)(NCOLS - 1 - (c0 + 2));
        u64 m3 = ((u64)fsort(v.w) << 32) | (u32)(NCOLS - 1 - (c0 + 3));
        u64 m = m0;
        if (m1 > m) m = m1;
        if (m2 > m) m = m2;
        if (m3 > m) m = m3;
        m = wave_reduce_max(m);
        if (lane == 0) s_row[i][wv] = m;
    }
    size_t cp = (size_t)rb * NCOLS + c0;
    ast64(&g_colpart[cp + 0], b0);
    ast64(&g_colpart[cp + 1], b1);
    ast64(&g_colpart[cp + 2], b2);
    ast64(&g_colpart[cp + 3], b3);
    __syncthreads();
    if (tid < TROWS) {
        u64 m = s_row[tid][0];
        if (s_row[tid][1] > m) m = s_row[tid][1];
        if (s_row[tid][2] > m) m = s_row[tid][2];
        if (s_row[tid][3] > m) m = s_row[tid][3];
        ast64(&g_rowpart[cb * NROWS + (r0 + tid)], m);
    }
}

// ---------- Phase 2: mutual-best commit. One wave per row r ----------
__device__ __forceinline__ void phase_commit(int* __restrict__ out, int r, int lane) {
    u64 v = ald64(&g_rowpart[(lane & 15) * NROWS + r]);
    u64 key = wave_reduce_max(v);
    key = __shfl(key, 0);                       // broadcast
    int c = NCOLS - 1 - (int)(key & 0xFFFFFFFFu);

    u64 cp = ald64(&g_colpart[(size_t)lane * NCOLS + c]);
    u64 colmax = wave_reduce_max(cp);           // lane 0

    if (lane == 0) {
        ast64(&g_rowbest[r], key);
        out[r] = r;                             // identity row indices
        u64 mk = (key & 0xFFFFFFFF00000000ULL) | (u32)(NROWS - 1 - r);
        if (colmax == mk) {                     // mutual best -> commit
            ast32(&g_col_used[c], 1);
            ast32(&g_row_assigned[r], 1);
            out[NROWS + r] = c;
        } else {
            ast32(&g_row_assigned[r], 0);
            int p = aadd32(&g_cnt[0], 1);
            ast32(&g_rem[0][p], r);
        }
    }
}

// ---------- Per-round phase (256 threads, block = row r) ----------
__device__ __forceinline__ void phase_round(const float* __restrict__ cost,
                                            int* __restrict__ out, int t, int r,
                                            int tid, u64* s_part) {
    if (ald32(&g_row_assigned[r])) return;   // uniform across block

    u64 key = ald64(&g_rowbest[r]);
    int c = NCOLS - 1 - (int)(key & 0xFFFFFFFFu);
    if (ald32(&g_col_used[c])) {      // stale -> rescan excluding used cols
        u64 best = 0ULL;
        const float4* row = (const float4*)(cost + (size_t)r * NCOLS);
        const u64* used = (const u64*)g_col_used;
        for (int k = tid; k < NCOLS / 4; k += 256) {
            float4 v = row[k];
            u64 w0 = ald64(&used[k * 2 + 0]);   // cols c0, c0+1
            u64 w1 = ald64(&used[k * 2 + 1]);   // cols c0+2, c0+3
            int c0 = k * 4;
            if (!(u32)w0)         { u64 kk = ((u64)fsort(v.x) << 32) | (u32)(NCOLS - 1 - (c0 + 0)); if (kk > best) best = kk; }
            if (!(u32)(w0 >> 32)) { u64 kk = ((u64)fsort(v.y) << 32) | (u32)(NCOLS - 1 - (c0 + 1)); if (kk > best) best = kk; }
            if (!(u32)w1)         { u64 kk = ((u64)fsort(v.z) << 32) | (u32)(NCOLS - 1 - (c0 + 2)); if (kk > best) best = kk; }
            if (!(u32)(w1 >> 32)) { u64 kk = ((u64)fsort(v.w) << 32) | (u32)(NCOLS - 1 - (c0 + 3)); if (kk > best) best = kk; }
        }
        key = block_reduce_max(best, s_part);
        if (tid == 0) ast64(&g_rowbest[r], key);
        c = NCOLS - 1 - (int)(key & 0xFFFFFFFFu);
    }

    int n = ald32(&g_cnt[t]);
    const int* list = g_rem[t & 1];
    u64 mine = (key & 0xFFFFFFFF00000000ULL) | (u32)(NROWS - 1 - r);
    u64 mx = 0ULL;
    for (int j = tid; j < n; j += 256) {
        int rj = ald32(&list[j]);
        if (rj != r) {
            float x = cost[(size_t)rj * NCOLS + c];
            u64 kj = ((u64)fsort(x) << 32) | (u32)(NROWS - 1 - rj);
            if (kj > mx) mx = kj;
        }
    }
    mx = block_reduce_max(mx, s_part);
    if (tid == 0) {
        if (mine > mx) {              // unique max at col c among survivors
            ast32(&g_col_used[c], 1);
            ast32(&g_row_assigned[r], 1);
            out[NROWS + r] = c;
        } else {
            int p = aadd32(&g_cnt[t + 1], 1);
            ast32(&g_rem[(t + 1) & 1][p], r);
        }
    }
}

// ---------- Final serial cleanup, single block of 256 ----------
__device__ __forceinline__ void phase_finish(const float* __restrict__ cost,
                                             int* __restrict__ out, int tid,
                                             int (*s_rem)[NROWS], u64* s_part,
                                             int* s_nn) {
    if (tid == 0) s_nn[0] = ald32(&g_cnt[NROUNDS]);
    __syncthreads();
    int n = s_nn[0];
    if (n == 0) return;
    for (int i = tid; i < n; i += 256) s_rem[0][i] = ald32(&g_rem[NROUNDS & 1][i]);
    __syncthreads();
    int cur = 0;
    while (n > 0) {
        // rescan rows whose cached best col was taken
        for (int i = 0; i < n; i++) {
            int r = s_rem[cur][i];
            u64 key = ald64(&g_rowbest[r]);
            int c = NCOLS - 1 - (int)(key & 0xFFFFFFFFu);
            if (ald32(&g_col_used[c])) {
                u64 best = 0ULL;
                const float4* row = (const float4*)(cost + (size_t)r * NCOLS);
                const u64* used = (const u64*)g_col_used;
                for (int k = tid; k < NCOLS / 4; k += 256) {
                    float4 v = row[k];
                    u64 w0 = ald64(&used[k * 2 + 0]);
                    u64 w1 = ald64(&used[k * 2 + 1]);
                    int c0 = k * 4;
                    if (!(u32)w0)         { u64 kk = ((u64)fsort(v.x) << 32) | (u32)(NCOLS - 1 - (c0 + 0)); if (kk > best) best = kk; }
                    if (!(u32)(w0 >> 32)) { u64 kk = ((u64)fsort(v.y) << 32) | (u32)(NCOLS - 1 - (c0 + 1)); if (kk > best) best = kk; }
                    if (!(u32)w1)         { u64 kk = ((u64)fsort(v.z) << 32) | (u32)(NCOLS - 1 - (c0 + 2)); if (kk > best) best = kk; }
                    if (!(u32)(w1 >> 32)) { u64 kk = ((u64)fsort(v.w) << 32) | (u32)(NCOLS - 1 - (c0 + 3)); if (kk > best) best = kk; }
                }
                u64 m = block_reduce_max(best, s_part);
                if (tid == 0) ast64(&g_rowbest[r], m);
            }
        }
        __syncthreads();
        if (tid == 0) s_nn[1] = 0;
        __syncthreads();
        for (int base = 0; base < n; base += 256) {
            bool win = false; int myr = -1, myc = -1;
            if (base + tid < n) {
                int r = s_rem[cur][base + tid];
                u64 key = ald64(&g_rowbest[r]);
                int c = NCOLS - 1 - (int)(key & 0xFFFFFFFFu);
                u64 mine = (key & 0xFFFFFFFF00000000ULL) | (u32)(NROWS - 1 - r);
                win = true;
                for (int j = 0; j < n; j++) {
                    int rj = s_rem[cur][j];
                    if (rj == r) continue;
                    float x = cost[(size_t)rj * NCOLS + c];
                    u64 kj = ((u64)fsort(x) << 32) | (u32)(NROWS - 1 - rj);
                    if (kj > mine) { win = false; break; }
                }
                myr = r; myc = c;
            }
            if (win) {
                ast32(&g_col_used[myc], 1);
                ast32(&g_row_assigned[myr], 1);
                out[NROWS + myr] = myc;
            }
            if (base + tid < n && !win) {
                int p = atomicAdd(&s_nn[1], 1);
                s_rem[cur ^ 1][p] = myr;
            }
        }
        __syncthreads();
        n = s_nn[1];
        cur ^= 1;
        __syncthreads();
    }
}

// ---------- Fused kernel: all phases, one dispatch, fence-free barriers ----
__global__ void __launch_bounds__(256, 4)
k_fused(const float* __restrict__ cost, int* __restrict__ out) {
    __shared__ u64 s_row[TROWS][4];
    __shared__ u64 s_part[4];
    __shared__ int s_rem[2][NROWS];
    __shared__ int s_nn[2];
    const int bid = blockIdx.x;
    const int tid = threadIdx.x;

    phase_scan(cost, bid, tid, s_row);
    grid_barrier(bid, tid);

    if (tid < 64) phase_commit(out, bid, tid);
    grid_barrier(bid, tid);

    phase_round(cost, out, 0, bid, tid, s_part);
    grid_barrier(bid, tid);

    phase_round(cost, out, 1, bid, tid, s_part);
    grid_barrier(bid, tid);

    if (bid == 0) phase_finish(cost, out, tid, s_rem, s_part, s_nn);
}

// ---------- Fallback path (plain launches), used only if coop launch fails ----------
__global__ void __launch_bounds__(256) k_scan2(const float* __restrict__ cost) {
    __shared__ u64 s_row[TROWS][4];
    phase_scan(cost, blockIdx.x, threadIdx.x, s_row);
}
__global__ void __launch_bounds__(64) k_commit2(int* __restrict__ out) {
    phase_commit(out, blockIdx.x, threadIdx.x);
}
__global__ void __launch_bounds__(256) k_round2(const float* __restrict__ cost,
                                                int* __restrict__ out, int t) {
    __shared__ u64 s_part[4];
    phase_round(cost, out, t, blockIdx.x, threadIdx.x, s_part);
}
__global__ void __launch_bounds__(256) k_finish2(const float* __restrict__ cost,
                                                 int* __restrict__ out) {
    __shared__ int s_rem[2][NROWS];
    __shared__ u64 s_part[4];
    __shared__ int s_nn[2];
    phase_finish(cost, out, threadIdx.x, s_rem, s_part, s_nn);
}

extern "C" void kernel_launch(void* const* d_in, const int* in_sizes, int n_in,
                              void* d_out, int out_size, void* d_ws, size_t ws_size,
                              hipStream_t stream) {
    const float* cost = (const float*)d_in[0];
    int* out = (int*)d_out;

    void* args[] = {(void*)&cost, (void*)&out};
    hipError_t e = hipLaunchCooperativeKernel(k_fused, dim3(NBLK), dim3(256),
                                              args, 0u, stream);
    if (e != hipSuccess) {
        // cooperative launch refused -> proven multi-dispatch path
        k_scan2<<<NBLK, 256, 0, stream>>>(cost);
        k_commit2<<<NROWS, 64, 0, stream>>>(out);
        for (int t = 0; t < NROUNDS; ++t)
            k_round2<<<NROWS, 256, 0, stream>>>(cost, out, t);
        k_finish2<<<1, 256, 0, stream>>>(cost, out);
    }
}

// Round 4
// 152.143 us; speedup vs baseline: 7.0400x; 1.1168x over previous
//
#include <hip/hip_runtime.h>
#include <stdint.h>

#define NROWS 1024
#define NCOLS 16384
#define NRB 64        // row tiles (16 rows each)
#define NCB 16        // col tiles (1024 cols each)
#define TROWS 16      // rows per tile
#define NROUNDS 2
#define NBLK (NRB * NCB)   // 1024 blocks = 4/CU x 256 CU, all co-resident:
                           // launch_bounds(256,4) -> 4 blocks/CU guaranteed
                           // (24 VGPR, 9.2KB LDS - no resource limit hit),
                           // so a plain launch is safe for the spin barrier
                           // AND graph-capturable (coop API is not: round-3's
                           // timed graph silently captured the fallback path).

#define NLEAF 64
#define LEAFSZ (NBLK / NLEAF)   // 16 arrivals per leaf

typedef unsigned long long u64;
typedef unsigned int u32;

// Persistent device state. Everything is written each call before being read:
// partials + col_used/cnt by scan phase; rowbest/assigned/rem by commit phase.
__device__ u64 g_rowpart[NCB * NROWS];         // per col-tile row maxima
__device__ u64 g_colpart[(size_t)NRB * NCOLS]; // per row-tile col maxima (8 MB)
__device__ u64 g_rowbest[NROWS];               // key: (sortable<<32)|(NCOLS-1-col)
__device__ int g_col_used[NCOLS];
__device__ int g_row_assigned[NROWS];
__device__ int g_rem[2][NROWS];                // double-buffered remaining lists
__device__ int g_cnt[NROUNDS + 1];             // list counts per round

// Monotone (never-reset) tree-barrier counters. Zero-init at module load;
// all values advance in lockstep (1024 leaf arrivals = 64 root adds = 1 gen
// bump per barrier), so state is valid across launches and rocprof replays.
__device__ int g_bar_leaf[NLEAF * 32];         // one 128B line per leaf
__device__ int g_bar_root;
__device__ int g_bar_gen;

// ---- RELAXED agent-scope accessors: device-coherent via MALL, NO cache
// maintenance ops attached (the round-1/2 barrier cost was 2048 per-barrier
// buffer_wbl2/buffer_inv L2 tag-walks from __threadfence + ACQUIRE spins;
// ~200us/barrier at 1024 blocks, identical for cg::sync and custom tree;
// round-3 confirmed: removing them took the fused kernel 885 -> 82us).
__device__ __forceinline__ u64 ald64(const u64* p) {
    return __hip_atomic_load((u64*)p, __ATOMIC_RELAXED, __HIP_MEMORY_SCOPE_AGENT);
}
__device__ __forceinline__ void ast64(u64* p, u64 v) {
    __hip_atomic_store(p, v, __ATOMIC_RELAXED, __HIP_MEMORY_SCOPE_AGENT);
}
__device__ __forceinline__ int ald32(const int* p) {
    return __hip_atomic_load((int*)p, __ATOMIC_RELAXED, __HIP_MEMORY_SCOPE_AGENT);
}
__device__ __forceinline__ void ast32(int* p, int v) {
    __hip_atomic_store(p, v, __ATOMIC_RELAXED, __HIP_MEMORY_SCOPE_AGENT);
}
__device__ __forceinline__ int aadd32(int* p, int v) {
    return __hip_atomic_fetch_add(p, v, __ATOMIC_RELAXED, __HIP_MEMORY_SCOPE_AGENT);
}

// Fence-free grid barrier. Correctness chain: every thread drains its own
// vmem (stores acked at MALL) -> __syncthreads -> tid0 arrives. fetch_add
// return values give causal order leaf->root->gen at the MALL; a waiter that
// observes the gen bump therefore observes all pre-barrier MALL stores.
// gen snapshot must COMPLETE before our arrival can trigger the bump, hence
// the waitcnt between snapshot and arrive.
__device__ __forceinline__ void grid_barrier(int bid, int tid) {
    asm volatile("s_waitcnt vmcnt(0)" ::: "memory");   // all threads drain
    __syncthreads();
    if (tid == 0) {
        int gen = ald32(&g_bar_gen);
        asm volatile("s_waitcnt vmcnt(0)" ::: "memory");  // snapshot bound
        int leaf = (bid & (NLEAF - 1)) * 32;
        int v = aadd32(&g_bar_leaf[leaf], 1);
        if ((v & (LEAFSZ - 1)) == LEAFSZ - 1) {           // leaf complete
            int u = aadd32(&g_bar_root, 1);
            if ((u & (NLEAF - 1)) == NLEAF - 1) {         // grid complete
                aadd32(&g_bar_gen, 1);
            }
        }
        while (ald32(&g_bar_gen) == gen) {
            __builtin_amdgcn_s_sleep(8);   // ~512cy nap, no cache ops
        }
    }
    __syncthreads();
    asm volatile("" ::: "memory");
}

// Monotone float32 -> uint32 mapping (preserves <):
__device__ __forceinline__ u32 fsort(float x) {
    u32 u = __float_as_uint(x);
    return u ^ ((u32)((int)u >> 31) | 0x80000000u);
}

__device__ __forceinline__ u64 wave_reduce_max(u64 v) {
    for (int off = 32; off; off >>= 1) {
        u64 o = __shfl_down(v, off);
        if (o > v) v = o;
    }
    return v;   // valid in lane 0
}

// blockDim == 256 (4 waves)
__device__ __forceinline__ u64 block_reduce_max(u64 v, u64* s_part) {
    v = wave_reduce_max(v);
    int wave = threadIdx.x >> 6;
    if ((threadIdx.x & 63) == 0) s_part[wave] = v;
    __syncthreads();
    u64 b = s_part[0];
    for (int w = 1; w < 4; w++) if (s_part[w] > b) b = s_part[w];
    __syncthreads();
    return b;
}

// ---------- Phase 1: tile scan. fb in [0, NBLK), 256 threads ----------
// Tile = 16 rows x 1024 cols. Col maxima in registers -> agent colpart
// stores; row maxima via per-row wave shuffle-reduce. Absorbs state init.
__device__ __forceinline__ void phase_scan(const float* __restrict__ cost,
                                           int fb, int tid, u64 (*s_row)[4]) {
    const int cb = fb & (NCB - 1);
    const int rb = fb >> 4;
    const int cbase = cb * 1024;
    const int r0 = rb * TROWS;
    const int c0 = cbase + tid * 4;
    const int wv = tid >> 6, lane = tid & 63;

    if (rb == 0) {     // init: each cb-block zeroes its col_used slice (MALL)
        ast64((u64*)(g_col_used + cbase) + tid * 2 + 0, 0ULL);
        ast64((u64*)(g_col_used + cbase) + tid * 2 + 1, 0ULL);
        if (cb == 0 && tid <= NROUNDS) ast32(&g_cnt[tid], 0);
    }

    u64 b0 = 0, b1 = 0, b2 = 0, b3 = 0;
    for (int i = 0; i < TROWS; ++i) {
        int r = r0 + i;
        float4 v = *(const float4*)(cost + (size_t)r * NCOLS + c0);
        u32 rk = (u32)(NROWS - 1 - r);
        u64 k0 = ((u64)fsort(v.x) << 32) | rk;
        u64 k1 = ((u64)fsort(v.y) << 32) | rk;
        u64 k2 = ((u64)fsort(v.z) << 32) | rk;
        u64 k3 = ((u64)fsort(v.w) << 32) | rk;
        if (k0 > b0) b0 = k0;
        if (k1 > b1) b1 = k1;
        if (k2 > b2) b2 = k2;
        if (k3 > b3) b3 = k3;
        // row max for this row: re-key with column id (ties -> smaller col)
        u64 m0 = ((u64)fsort(v.x) << 32) | (u32)(NCOLS - 1 - (c0 + 0));
        u64 m1 = ((u64)fsort(v.y) << 32) | (u32)(NCOLS - 1 - (c0 + 1));
        u64 m2 = ((u64)fsort(v.z) << 32) | (u32)(NCOLS - 1 - (c0 + 2));
        u64 m3 = ((u64)fsort(v.w) << 32) | (u32)(NCOLS - 1 - (c0 + 3));
        u64 m = m0;
        if (m1 > m) m = m1;
        if (m2 > m) m = m2;
        if (m3 > m) m = m3;
        m = wave_reduce_max(m);
        if (lane == 0) s_row[i][wv] = m;
    }
    size_t cp = (size_t)rb * NCOLS + c0;
    ast64(&g_colpart[cp + 0], b0);
    ast64(&g_colpart[cp + 1], b1);
    ast64(&g_colpart[cp + 2], b2);
    ast64(&g_colpart[cp + 3], b3);
    __syncthreads();
    if (tid < TROWS) {
        u64 m = s_row[tid][0];
        if (s_row[tid][1] > m) m = s_row[tid][1];
        if (s_row[tid][2] > m) m = s_row[tid][2];
        if (s_row[tid][3] > m) m = s_row[tid][3];
        ast64(&g_rowpart[cb * NROWS + (r0 + tid)], m);
    }
}

// ---------- Phase 2: mutual-best commit. One wave per row r ----------
__device__ __forceinline__ void phase_commit(int* __restrict__ out, int r, int lane) {
    u64 v = ald64(&g_rowpart[(lane & 15) * NROWS + r]);
    u64 key = wave_reduce_max(v);
    key = __shfl(key, 0);                       // broadcast
    int c = NCOLS - 1 - (int)(key & 0xFFFFFFFFu);

    u64 cp = ald64(&g_colpart[(size_t)lane * NCOLS + c]);
    u64 colmax = wave_reduce_max(cp);           // lane 0

    if (lane == 0) {
        ast64(&g_rowbest[r], key);
        out[r] = r;                             // identity row indices
        u64 mk = (key & 0xFFFFFFFF00000000ULL) | (u32)(NROWS - 1 - r);
        if (colmax == mk) {                     // mutual best -> commit
            ast32(&g_col_used[c], 1);
            ast32(&g_row_assigned[r], 1);
            out[NROWS + r] = c;
        } else {
            ast32(&g_row_assigned[r], 0);
            int p = aadd32(&g_cnt[0], 1);
            ast32(&g_rem[0][p], r);
        }
    }
}

// ---------- Per-round phase (256 threads, block = row r) ----------
__device__ __forceinline__ void phase_round(const float* __restrict__ cost,
                                            int* __restrict__ out, int t, int r,
                                            int tid, u64* s_part) {
    if (ald32(&g_row_assigned[r])) return;   // uniform across block

    u64 key = ald64(&g_rowbest[r]);
    int c = NCOLS - 1 - (int)(key & 0xFFFFFFFFu);
    if (ald32(&g_col_used[c])) {      // stale -> rescan excluding used cols
        u64 best = 0ULL;
        const float4* row = (const float4*)(cost + (size_t)r * NCOLS);
        const u64* used = (const u64*)g_col_used;
        for (int k = tid; k < NCOLS / 4; k += 256) {
            float4 v = row[k];
            u64 w0 = ald64(&used[k * 2 + 0]);   // cols c0, c0+1
            u64 w1 = ald64(&used[k * 2 + 1]);   // cols c0+2, c0+3
            int c0 = k * 4;
            if (!(u32)w0)         { u64 kk = ((u64)fsort(v.x) << 32) | (u32)(NCOLS - 1 - (c0 + 0)); if (kk > best) best = kk; }
            if (!(u32)(w0 >> 32)) { u64 kk = ((u64)fsort(v.y) << 32) | (u32)(NCOLS - 1 - (c0 + 1)); if (kk > best) best = kk; }
            if (!(u32)w1)         { u64 kk = ((u64)fsort(v.z) << 32) | (u32)(NCOLS - 1 - (c0 + 2)); if (kk > best) best = kk; }
            if (!(u32)(w1 >> 32)) { u64 kk = ((u64)fsort(v.w) << 32) | (u32)(NCOLS - 1 - (c0 + 3)); if (kk > best) best = kk; }
        }
        key = block_reduce_max(best, s_part);
        if (tid == 0) ast64(&g_rowbest[r], key);
        c = NCOLS - 1 - (int)(key & 0xFFFFFFFFu);
    }

    int n = ald32(&g_cnt[t]);
    const int* list = g_rem[t & 1];
    u64 mine = (key & 0xFFFFFFFF00000000ULL) | (u32)(NROWS - 1 - r);
    u64 mx = 0ULL;
    for (int j = tid; j < n; j += 256) {
        int rj = ald32(&list[j]);
        if (rj != r) {
            float x = cost[(size_t)rj * NCOLS + c];
            u64 kj = ((u64)fsort(x) << 32) | (u32)(NROWS - 1 - rj);
            if (kj > mx) mx = kj;
        }
    }
    mx = block_reduce_max(mx, s_part);
    if (tid == 0) {
        if (mine > mx) {              // unique max at col c among survivors
            ast32(&g_col_used[c], 1);
            ast32(&g_row_assigned[r], 1);
            out[NROWS + r] = c;
        } else {
            int p = aadd32(&g_cnt[t + 1], 1);
            ast32(&g_rem[(t + 1) & 1][p], r);
        }
    }
}

// ---------- Final serial cleanup, single block of 256 ----------
__device__ __forceinline__ void phase_finish(const float* __restrict__ cost,
                                             int* __restrict__ out, int tid,
                                             int (*s_rem)[NROWS], u64* s_part,
                                             int* s_nn) {
    if (tid == 0) s_nn[0] = ald32(&g_cnt[NROUNDS]);
    __syncthreads();
    int n = s_nn[0];
    if (n == 0) return;
    for (int i = tid; i < n; i += 256) s_rem[0][i] = ald32(&g_rem[NROUNDS & 1][i]);
    __syncthreads();
    int cur = 0;
    while (n > 0) {
        // rescan rows whose cached best col was taken
        for (int i = 0; i < n; i++) {
            int r = s_rem[cur][i];
            u64 key = ald64(&g_rowbest[r]);
            int c = NCOLS - 1 - (int)(key & 0xFFFFFFFFu);
            if (ald32(&g_col_used[c])) {
                u64 best = 0ULL;
                const float4* row = (const float4*)(cost + (size_t)r * NCOLS);
                const u64* used = (const u64*)g_col_used;
                for (int k = tid; k < NCOLS / 4; k += 256) {
                    float4 v = row[k];
                    u64 w0 = ald64(&used[k * 2 + 0]);
                    u64 w1 = ald64(&used[k * 2 + 1]);
                    int c0 = k * 4;
                    if (!(u32)w0)         { u64 kk = ((u64)fsort(v.x) << 32) | (u32)(NCOLS - 1 - (c0 + 0)); if (kk > best) best = kk; }
                    if (!(u32)(w0 >> 32)) { u64 kk = ((u64)fsort(v.y) << 32) | (u32)(NCOLS - 1 - (c0 + 1)); if (kk > best) best = kk; }
                    if (!(u32)w1)         { u64 kk = ((u64)fsort(v.z) << 32) | (u32)(NCOLS - 1 - (c0 + 2)); if (kk > best) best = kk; }
                    if (!(u32)(w1 >> 32)) { u64 kk = ((u64)fsort(v.w) << 32) | (u32)(NCOLS - 1 - (c0 + 3)); if (kk > best) best = kk; }
                }
                u64 m = block_reduce_max(best, s_part);
                if (tid == 0) ast64(&g_rowbest[r], m);
            }
        }
        __syncthreads();
        if (tid == 0) s_nn[1] = 0;
        __syncthreads();
        for (int base = 0; base < n; base += 256) {
            bool win = false; int myr = -1, myc = -1;
            if (base + tid < n) {
                int r = s_rem[cur][base + tid];
                u64 key = ald64(&g_rowbest[r]);
                int c = NCOLS - 1 - (int)(key & 0xFFFFFFFFu);
                u64 mine = (key & 0xFFFFFFFF00000000ULL) | (u32)(NROWS - 1 - r);
                win = true;
                for (int j = 0; j < n; j++) {
                    int rj = s_rem[cur][j];
                    if (rj == r) continue;
                    float x = cost[(size_t)rj * NCOLS + c];
                    u64 kj = ((u64)fsort(x) << 32) | (u32)(NROWS - 1 - rj);
                    if (kj > mine) { win = false; break; }
                }
                myr = r; myc = c;
            }
            if (win) {
                ast32(&g_col_used[myc], 1);
                ast32(&g_row_assigned[myr], 1);
                out[NROWS + myr] = myc;
            }
            if (base + tid < n && !win) {
                int p = atomicAdd(&s_nn[1], 1);
                s_rem[cur ^ 1][p] = myr;
            }
        }
        __syncthreads();
        n = s_nn[1];
        cur ^= 1;
        __syncthreads();
    }
}

// ---------- Fused kernel: all phases, one dispatch, fence-free barriers ----
// Plain (non-cooperative) launch: co-residency of all 1024 blocks is
// guaranteed by launch_bounds(256,4) x 256 CUs, and plain launches ARE
// graph-capturable (cooperative ones are not - round 3's timed graph
// silently captured the multi-kernel fallback instead of this kernel).
__global__ void __launch_bounds__(256, 4)
k_fused(const float* __restrict__ cost, int* __restrict__ out) {
    __shared__ u64 s_row[TROWS][4];
    __shared__ u64 s_part[4];
    __shared__ int s_rem[2][NROWS];
    __shared__ int s_nn[2];
    const int bid = blockIdx.x;
    const int tid = threadIdx.x;

    phase_scan(cost, bid, tid, s_row);
    grid_barrier(bid, tid);

    if (tid < 64) phase_commit(out, bid, tid);
    grid_barrier(bid, tid);

    phase_round(cost, out, 0, bid, tid, s_part);
    grid_barrier(bid, tid);

    phase_round(cost, out, 1, bid, tid, s_part);
    grid_barrier(bid, tid);

    if (bid == 0) phase_finish(cost, out, tid, s_rem, s_part, s_nn);
}

extern "C" void kernel_launch(void* const* d_in, const int* in_sizes, int n_in,
                              void* d_out, int out_size, void* d_ws, size_t ws_size,
                              hipStream_t stream) {
    const float* cost = (const float*)d_in[0];
    int* out = (int*)d_out;
    k_fused<<<dim3(NBLK), dim3(256), 0, stream>>>(cost, out);
}